// Round 5
// baseline (252.440 us; speedup 1.0000x reference)
//
#include <hip/hip_runtime.h>
#include <stdint.h>

// Problem constants (B=2,S=2048 -> BS=4096). ALL inputs/outputs are FP32.
#define BSZ   4096    // B*S tokens
#define DIM   1024    // D
#define WTR   4096    // W trees
#define KDIM  4096    // GEMM K == W
#define W8    32768   // W*8 leaf-rows

typedef unsigned short u16;
typedef _Float16 half2_t __attribute__((ext_vector_type(2)));
typedef __attribute__((ext_vector_type(8))) short bhalf8;     // 8 x bf16 (4 VGPRs)
typedef __attribute__((ext_vector_type(4))) float floatx4;    // 16x16 MFMA acc

__device__ __forceinline__ u16 f2bf(float f) {
    union { float f; uint32_t i; } v; v.f = f;
    uint32_t r = v.i + 0x7fffu + ((v.i >> 16) & 1u);   // round-nearest-even
    return (u16)(r >> 16);
}
__device__ __forceinline__ u16 f2h(float f) {
    union { _Float16 h; u16 u; } v; v.h = (_Float16)f;
    return v.u;
}
// tanh(x) = 1 - 2/(exp2(x*2*log2e)+1)
__device__ __forceinline__ float fast_tanh(float x) {
    float e = __builtin_amdgcn_exp2f(x * 2.885390081777927f);
    return fmaf(-2.0f, __builtin_amdgcn_rcpf(e + 1.0f), 1.0f);
}
__device__ __forceinline__ float dot2(uint32_t a, uint32_t b, float c) {
    union { uint32_t u; half2_t h; } ua, ub; ua.u = a; ub.u = b;
#if __has_builtin(__builtin_amdgcn_fdot2)
    return __builtin_amdgcn_fdot2(ua.h, ub.h, c, false);
#else
    c = fmaf((float)ua.h[0], (float)ub.h[0], c);
    return fmaf((float)ua.h[1], (float)ub.h[1], c);
#endif
}
__device__ __forceinline__ void load16(const void* g, void* lds) {
    __builtin_amdgcn_global_load_lds(
        (const __attribute__((address_space(1))) uint32_t*)g,
        (__attribute__((address_space(3))) uint32_t*)lds, 16, 0, 0);
}

// ---- kernel 0 (fused prep): selector softmax -> f16; out_w^T bf16; slot_w^T --
__global__ __launch_bounds__(256) void k_prep(const float* __restrict__ ll,
                                              u16* __restrict__ selwA2,
                                              const float* __restrict__ ow,
                                              u16* __restrict__ owt,
                                              const float* __restrict__ slot_w,
                                              u16* __restrict__ swT) {
    int bid = blockIdx.x, tid = threadIdx.x;
    if (bid < 128) {                       // ---- selector: 32768 rows
        int row = bid * 256 + tid;
        const float* p = ll + (size_t)row * 11;
        float v[11]; float m = -1e30f;
        #pragma unroll
        for (int c = 0; c < 11; ++c) { v[c] = p[c]; m = fmaxf(m, v[c]); }
        float s = 0.f;
        #pragma unroll
        for (int c = 0; c < 11; ++c) {
            v[c] = __builtin_amdgcn_exp2f((v[c] - m) * 1.4426950408889634f);
            s += v[c];
        }
        float inv = __builtin_amdgcn_rcpf(s);
        union { u16 h[16]; uint4 q[2]; } o;
        #pragma unroll
        for (int c = 0; c < 8; ++c) o.h[c] = f2h(v[c] * inv);
        o.h[8] = f2h((v[10] - v[8]) * inv);
        #pragma unroll
        for (int c = 9; c < 16; ++c) o.h[c] = 0;
        uint4* dst = (uint4*)(selwA2 + (size_t)row * 16);
        dst[0] = o.q[0]; dst[1] = o.q[1];
    } else if (bid < 128 + 4096) {         // ---- out_w (W,D) -> owt (D,W) bf16
        int b = bid - 128;
        int d0 = (b & 31) * 32, w0 = (b >> 5) * 32;
        int tx = tid & 31, ty = tid >> 5;
        __shared__ float tile[32][33];
        #pragma unroll
        for (int i = 0; i < 32; i += 8)
            tile[ty + i][tx] = ow[(size_t)(w0 + ty + i) * DIM + d0 + tx];
        __syncthreads();
        #pragma unroll
        for (int i = 0; i < 32; i += 8)
            owt[(size_t)(d0 + ty + i) * WTR + w0 + tx] = f2bf(tile[tx][ty + i]);
    } else {                               // ---- slot_w (D,8) -> swT (16,D) bf16
        int b = bid - 128 - 4096;
        for (int it = 0; it < 8; ++it) {
            int idx = b * 2048 + it * 256 + tid;
            int s = idx >> 10, d = idx & 1023;
            float val = (s < 8) ? slot_w[(size_t)d * 8 + s] : 0.f;
            swT[(size_t)s * DIM + d] = f2bf(val);
        }
    }
}

// ---- kernel 1: basisF16[t][16] f16 via MFMA, 4 waves K-split + LDS reduce ----
// block = 16 tokens, wave w handles K slice [w*256, w*256+256)
__global__ __launch_bounds__(256) void k_basis(const float* __restrict__ hidden,
                                               const u16* __restrict__ swT,
                                               const float* __restrict__ slot_b,
                                               u16* __restrict__ basisF16) {
    int m0 = blockIdx.x * 16;
    int tid = threadIdx.x, lane = tid & 63, wid = tid >> 6;
    int col = lane & 15, quad = lane >> 4;
    const float* ga = hidden + (size_t)(m0 + col) * DIM + wid * 256 + quad * 8;
    const u16*   gb = swT + (size_t)col * DIM + wid * 256 + quad * 8;
    floatx4 acc = (floatx4){0.f, 0.f, 0.f, 0.f};
    #pragma unroll
    for (int k0 = 0; k0 < 256; k0 += 32) {
        float4 a0 = *(const float4*)(ga + k0);
        float4 a1 = *(const float4*)(ga + k0 + 4);
        bhalf8 bf = *(const bhalf8*)(gb + k0);
        bhalf8 af;
        af[0] = (short)f2bf(a0.x); af[1] = (short)f2bf(a0.y);
        af[2] = (short)f2bf(a0.z); af[3] = (short)f2bf(a0.w);
        af[4] = (short)f2bf(a1.x); af[5] = (short)f2bf(a1.y);
        af[6] = (short)f2bf(a1.z); af[7] = (short)f2bf(a1.w);
        acc = __builtin_amdgcn_mfma_f32_16x16x32_bf16(af, bf, acc, 0, 0, 0);
    }
    __shared__ float smr[4][16][16];   // [wave][token][col]
    #pragma unroll
    for (int r = 0; r < 4; ++r) smr[wid][quad * 4 + r][col] = acc[r];
    __syncthreads();
    // one thread per (token, col) of the 16x16 tile
    int tt = tid >> 4, cc = tid & 15;
    float s = smr[0][tt][cc] + smr[1][tt][cc] + smr[2][tt][cc] + smr[3][tt][cc];
    u16 val;
    if (cc < 8)       val = f2h(fast_tanh(s + slot_b[cc]));
    else if (cc == 8) val = (u16)0x3C00;   // f16 1.0
    else              val = 0;
    basisF16[(size_t)(m0 + tt) * 16 + cc] = val;
}

// ---- kernel 2: roots = tree(selector @ basis), thread = tree, 2-token ILP ----
#define TB 64
__global__ __launch_bounds__(256, 4) void k_roots(const u16* __restrict__ selwA2,
                                                  const u16* __restrict__ basisF16,
                                                  const float* __restrict__ np_,
                                                  u16* __restrict__ roots) {
    int w  = blockIdx.x * 256 + threadIdx.x;
    int t0 = blockIdx.y * TB;
    float lw = np_[0], rw = np_[1], pw = np_[2], dw = np_[3], nb = np_[4];

    uint32_t wv[8][5];
    const uint32_t* sp = (const uint32_t*)(selwA2 + (size_t)w * 8 * 16);
    #pragma unroll
    for (int l = 0; l < 8; ++l) {
        uint4 q = *(const uint4*)(sp + l * 8);
        wv[l][0] = q.x; wv[l][1] = q.y; wv[l][2] = q.z; wv[l][3] = q.w;
        wv[l][4] = sp[l * 8 + 4];
    }
    __shared__ uint32_t sb[TB * 8];
    {
        const uint32_t* gbs = (const uint32_t*)basisF16 + (size_t)t0 * 8;
        for (int i = threadIdx.x; i < TB * 8; i += 256) sb[i] = gbs[i];
    }
    __syncthreads();

    for (int tt = 0; tt < TB; tt += 2) {    // 2 tokens per iter: indep chains
        uint4 q0 = *(const uint4*)(sb + tt * 8);
        uint4 q1 = *(const uint4*)(sb + tt * 8 + 8);
        uint32_t b0[5] = {q0.x, q0.y, q0.z, q0.w, sb[tt * 8 + 4]};
        uint32_t b1[5] = {q1.x, q1.y, q1.z, q1.w, sb[tt * 8 + 12]};
        float v0[8], v1[8];
        #pragma unroll
        for (int l = 0; l < 8; ++l) {
            float a0 = 0.f, a1 = 0.f;
            #pragma unroll
            for (int p = 0; p < 5; ++p) {
                a0 = dot2(wv[l][p], b0[p], a0);
                a1 = dot2(wv[l][p], b1[p], a1);
            }
            v0[l] = a0; v1[l] = a1;
        }
        #pragma unroll
        for (int lev = 0; lev < 3; ++lev) {
            int n = 4 >> lev;
            #pragma unroll
            for (int i = 0; i < 4; ++i) {
                if (i < n) {
                    float L0 = v0[2*i], R0 = v0[2*i+1];
                    float x0 = fmaf(lw, L0, nb);
                    x0 = fmaf(rw, R0, x0);
                    x0 = fmaf(pw, L0 * R0, x0);
                    x0 = fmaf(dw, L0 - R0, x0);
                    float L1 = v1[2*i], R1 = v1[2*i+1];
                    float x1 = fmaf(lw, L1, nb);
                    x1 = fmaf(rw, R1, x1);
                    x1 = fmaf(pw, L1 * R1, x1);
                    x1 = fmaf(dw, L1 - R1, x1);
                    v0[i] = fast_tanh(x0);
                    v1[i] = fast_tanh(x1);
                }
            }
        }
        roots[(size_t)(t0 + tt)     * WTR + w] = f2bf(v0[0]);
        roots[(size_t)(t0 + tt + 1) * WTR + w] = f2bf(v1[0]);
    }
}

// ---- kernel 3: out = roots @ out_w + out_b -----------------------------------
// BM=64 BN=128 BK=64, grid (64,8)=512 blocks = 2/CU, double-buffered LDS,
// ONE barrier per K-iter; prefetch issued post-barrier overlaps ds_read+MFMA.
// 4 waves (2x2), wave tile 32x64 = 2x4 mfma16 frags x 2 k-chunks
__global__ __launch_bounds__(256) void k_gemm(const u16* __restrict__ A,
                                              const u16* __restrict__ Bt,
                                              const float* __restrict__ out_b,
                                              float* __restrict__ C) {
    __shared__ __align__(16) u16 smA[2][64 * 64];    // 2 x 8 KB
    __shared__ __align__(16) u16 smB[2][128 * 64];   // 2 x 16 KB
    int tid = threadIdx.x;
    int bm = blockIdx.x * 64, bn = blockIdx.y * 128;
    int lane = tid & 63, wid = tid >> 6;
    int wm = (wid >> 1) * 32, wn = (wid & 1) * 64;

    floatx4 acc[2][4];
    #pragma unroll
    for (int i = 0; i < 2; ++i)
        #pragma unroll
        for (int j = 0; j < 4; ++j) acc[i][j] = (floatx4){0.f, 0.f, 0.f, 0.f};

    int ar = tid >> 3;            // 0..31 (staging row)
    int ak = (tid & 7) * 8;       // 0..56 (staging k elem)
    const u16* gA = A  + (size_t)(bm + ar) * KDIM + ak;
    const u16* gB = Bt + (size_t)(bn + ar) * KDIM + ak;

    int col = lane & 15, quad = lane >> 4;

    // preload iter 0 into buf 0
    {
        char* ldA = (char*)smA[0] + tid * 16;
        char* ldB = (char*)smB[0] + tid * 16;
        load16(gA,                       ldA);
        load16(gA + (size_t)32 * KDIM,   ldA + 4096);
        load16(gB,                       ldB);
        load16(gB + (size_t)32 * KDIM,   ldB + 4096);
        load16(gB + (size_t)64 * KDIM,   ldB + 8192);
        load16(gB + (size_t)96 * KDIM,   ldB + 12288);
        gA += 64; gB += 64;
    }

    int cur = 0;
    for (int k0 = 0; k0 < KDIM / 64; ++k0) {
        __syncthreads();   // buf[cur] staged (drains prefetch issued last iter)
        if (k0 < KDIM / 64 - 1) {
            char* ldA = (char*)smA[cur ^ 1] + tid * 16;
            char* ldB = (char*)smB[cur ^ 1] + tid * 16;
            load16(gA,                       ldA);
            load16(gA + (size_t)32 * KDIM,   ldA + 4096);
            load16(gB,                       ldB);
            load16(gB + (size_t)32 * KDIM,   ldB + 4096);
            load16(gB + (size_t)64 * KDIM,   ldB + 8192);
            load16(gB + (size_t)96 * KDIM,   ldB + 12288);
            gA += 64; gB += 64;
        }
        const u16* sa = smA[cur];
        const u16* sb = smB[cur];
        #pragma unroll
        for (int kk = 0; kk < 2; ++kk) {
            int ko = kk * 32 + quad * 8;
            bhalf8 af[2], bf[4];
            #pragma unroll
            for (int i = 0; i < 2; ++i)
                af[i] = *(const bhalf8*)(sa + (wm + i * 16 + col) * 64 + ko);
            #pragma unroll
            for (int j = 0; j < 4; ++j)
                bf[j] = *(const bhalf8*)(sb + (wn + j * 16 + col) * 64 + ko);
            #pragma unroll
            for (int i = 0; i < 2; ++i)
                #pragma unroll
                for (int j = 0; j < 4; ++j)
                    acc[i][j] = __builtin_amdgcn_mfma_f32_16x16x32_bf16(
                        af[i], bf[j], acc[i][j], 0, 0, 0);
        }
        cur ^= 1;
    }

    #pragma unroll
    for (int j = 0; j < 4; ++j) {
        int n = bn + wn + j * 16 + col;
        float bv = out_b[n];
        #pragma unroll
        for (int i = 0; i < 2; ++i) {
            int m0 = bm + wm + i * 16 + quad * 4;
            #pragma unroll
            for (int r = 0; r < 4; ++r)
                C[(size_t)(m0 + r) * DIM + n] = acc[i][j][r] + bv;
        }
    }
}

// ---------------- launcher ----------------------------------------------------
extern "C" void kernel_launch(void* const* d_in, const int* in_sizes, int n_in,
                              void* d_out, int out_size, void* d_ws, size_t ws_size,
                              hipStream_t stream) {
    const float* hidden      = (const float*)d_in[0];
    const float* slot_w      = (const float*)d_in[1];
    const float* slot_b      = (const float*)d_in[2];
    const float* leaf_logits = (const float*)d_in[3];
    const float* node_params = (const float*)d_in[4];
    const float* out_w       = (const float*)d_in[5];
    const float* out_b       = (const float*)d_in[6];
    float* out = (float*)d_out;

    char* ws = (char*)d_ws;
    u16* selwA2   = (u16*)ws;                         // 32768*32B   = 1048576
    u16* basisF16 = (u16*)(ws + 1048576);             // 4096*32B    = 131072
    u16* swT      = (u16*)(ws + 1179648);             // 16*1024*2   = 32768
    u16* outwt    = (u16*)(ws + 1212416);             // 1024*4096*2 = 8388608
    u16* roots    = (u16*)(ws + 9601024);             // 4096*4096*2 = 33554432

    k_prep <<<128 + 4096 + 8, 256, 0, stream>>>(leaf_logits, selwA2, out_w, outwt, slot_w, swT);
    k_basis<<<BSZ / 16, 256, 0, stream>>>(hidden, swT, slot_b, basisF16);
    k_roots<<<dim3(WTR / 256, BSZ / TB), 256, 0, stream>>>(selwA2, basisF16, node_params, roots);
    k_gemm <<<dim3(BSZ / 64, DIM / 128), 256, 0, stream>>>(roots, outwt, out_b, out);
}

// Round 6
// 206.788 us; speedup vs baseline: 1.2208x; 1.2208x over previous
//
#include <hip/hip_runtime.h>
#include <stdint.h>

// Problem constants (B=2,S=2048 -> BS=4096). ALL inputs/outputs are FP32.
#define BSZ   4096    // B*S tokens
#define DIM   1024    // D
#define WTR   4096    // W trees
#define KDIM  4096    // GEMM K == W
#define W8    32768   // W*8 leaf-rows

typedef unsigned short u16;
typedef __attribute__((ext_vector_type(8))) short bhalf8;     // 8 x bf16 (4 VGPRs)
typedef __attribute__((ext_vector_type(4))) float floatx4;    // 16x16 MFMA acc
typedef __attribute__((ext_vector_type(16))) float floatx16;  // 32x32 MFMA acc

__device__ __forceinline__ u16 f2bf(float f) {
    union { float f; uint32_t i; } v; v.f = f;
    uint32_t r = v.i + 0x7fffu + ((v.i >> 16) & 1u);   // round-nearest-even
    return (u16)(r >> 16);
}
// tanh(x) = 1 - 2/(exp2(x*2*log2e)+1)
__device__ __forceinline__ float fast_tanh(float x) {
    float e = __builtin_amdgcn_exp2f(x * 2.885390081777927f);
    return fmaf(-2.0f, __builtin_amdgcn_rcpf(e + 1.0f), 1.0f);
}
__device__ __forceinline__ void load16(const void* g, void* lds) {
    __builtin_amdgcn_global_load_lds(
        (const __attribute__((address_space(1))) uint32_t*)g,
        (__attribute__((address_space(3))) uint32_t*)lds, 16, 0, 0);
}

// ---- kernel 0 (fused prep): selector softmax -> bf16 A (PERMUTED rows);
//      out_w^T bf16; slot_w^T bf16 ---------------------------------------------
// Leaf-row (w,l) placed at MFMA row p = (l&3)+8*(l>>2)+16*(q&1)+4*(q>>1), q=w&3,
// within tile (w>>2). After mfma_32x32x16, lane h=lane>>5 holds tree 2h in regs
// 0-7 (leaves in order) and tree 2h+1 in regs 8-15 -> no cross-lane exchange.
__global__ __launch_bounds__(256) void k_prep(const float* __restrict__ ll,
                                              u16* __restrict__ selwA,
                                              const float* __restrict__ ow,
                                              u16* __restrict__ owt,
                                              const float* __restrict__ slot_w,
                                              u16* __restrict__ swT) {
    int bid = blockIdx.x, tid = threadIdx.x;
    if (bid < 128) {                       // ---- selector: 32768 rows
        int row = bid * 256 + tid;         // w*8 + l
        int w = row >> 3, l = row & 7, q = w & 3;
        int prow = (w >> 2) * 32 + (l & 3) + 8 * (l >> 2) + 16 * (q & 1) + 4 * (q >> 1);
        const float* p = ll + (size_t)row * 11;
        float v[11]; float m = -1e30f;
        #pragma unroll
        for (int c = 0; c < 11; ++c) { v[c] = p[c]; m = fmaxf(m, v[c]); }
        float s = 0.f;
        #pragma unroll
        for (int c = 0; c < 11; ++c) {
            v[c] = __builtin_amdgcn_exp2f((v[c] - m) * 1.4426950408889634f);
            s += v[c];
        }
        float inv = __builtin_amdgcn_rcpf(s);
        union { u16 h[16]; uint4 qq[2]; } o;
        #pragma unroll
        for (int c = 0; c < 8; ++c) o.h[c] = f2bf(v[c] * inv);
        o.h[8] = f2bf((v[10] - v[8]) * inv);   // consts -1,0,1 folded (basis k8=1)
        #pragma unroll
        for (int c = 9; c < 16; ++c) o.h[c] = 0;
        uint4* dst = (uint4*)(selwA + (size_t)prow * 16);
        dst[0] = o.qq[0]; dst[1] = o.qq[1];
    } else if (bid < 128 + 4096) {         // ---- out_w (W,D) -> owt (D,W) bf16
        int b = bid - 128;
        int d0 = (b & 31) * 32, w0 = (b >> 5) * 32;
        int tx = tid & 31, ty = tid >> 5;
        __shared__ float tile[32][33];
        #pragma unroll
        for (int i = 0; i < 32; i += 8)
            tile[ty + i][tx] = ow[(size_t)(w0 + ty + i) * DIM + d0 + tx];
        __syncthreads();
        #pragma unroll
        for (int i = 0; i < 32; i += 8)
            owt[(size_t)(d0 + ty + i) * WTR + w0 + tx] = f2bf(tile[tx][ty + i]);
    } else {                               // ---- slot_w (D,8) -> swT (16,D) bf16
        int b = bid - 128 - 4096;
        for (int it = 0; it < 8; ++it) {
            int idx = b * 2048 + it * 256 + tid;
            int s = idx >> 10, d = idx & 1023;
            float val = (s < 8) ? slot_w[(size_t)d * 8 + s] : 0.f;
            swT[(size_t)s * DIM + d] = f2bf(val);
        }
    }
}

// ---- kernel 1: basisTB[t][16] bf16 via MFMA, 4 waves K-split + LDS reduce ----
__global__ __launch_bounds__(256) void k_basis(const float* __restrict__ hidden,
                                               const u16* __restrict__ swT,
                                               const float* __restrict__ slot_b,
                                               u16* __restrict__ basisTB) {
    int m0 = blockIdx.x * 16;
    int tid = threadIdx.x, lane = tid & 63, wid = tid >> 6;
    int col = lane & 15, quad = lane >> 4;
    const float* ga = hidden + (size_t)(m0 + col) * DIM + wid * 256 + quad * 8;
    const u16*   gb = swT + (size_t)col * DIM + wid * 256 + quad * 8;
    floatx4 acc = (floatx4){0.f, 0.f, 0.f, 0.f};
    #pragma unroll
    for (int k0 = 0; k0 < 256; k0 += 32) {
        float4 a0 = *(const float4*)(ga + k0);
        float4 a1 = *(const float4*)(ga + k0 + 4);
        bhalf8 bf = *(const bhalf8*)(gb + k0);
        bhalf8 af;
        af[0] = (short)f2bf(a0.x); af[1] = (short)f2bf(a0.y);
        af[2] = (short)f2bf(a0.z); af[3] = (short)f2bf(a0.w);
        af[4] = (short)f2bf(a1.x); af[5] = (short)f2bf(a1.y);
        af[6] = (short)f2bf(a1.z); af[7] = (short)f2bf(a1.w);
        acc = __builtin_amdgcn_mfma_f32_16x16x32_bf16(af, bf, acc, 0, 0, 0);
    }
    __shared__ float smr[4][16][16];   // [wave][token][col]
    #pragma unroll
    for (int r = 0; r < 4; ++r) smr[wid][quad * 4 + r][col] = acc[r];
    __syncthreads();
    int tt = tid >> 4, cc = tid & 15;
    float s = smr[0][tt][cc] + smr[1][tt][cc] + smr[2][tt][cc] + smr[3][tt][cc];
    u16 val;
    if (cc < 8)       val = f2bf(fast_tanh(s + slot_b[cc]));
    else if (cc == 8) val = (u16)0x3f80;   // bf16 1.0
    else              val = 0;
    basisTB[(size_t)(m0 + tt) * 16 + cc] = val;
}

// ---- kernel 2: roots via MFMA einsum (permuted A) + in-register tree ---------
// wave = 4 row-tiles (16 trees) x 32-token strip; lane owns 2 full trees/tile.
// LDS repack -> coalesced 32B root stores. grid (64, 8) = 512 blocks.
__device__ __forceinline__ float tree_eval(float v[8], float lw, float rw,
                                           float pw, float dw, float nb) {
    #pragma unroll
    for (int lev = 0; lev < 3; ++lev) {
        int n = 4 >> lev;
        #pragma unroll
        for (int i = 0; i < 4; ++i) {
            if (i < n) {
                float L = v[2*i], R = v[2*i+1];
                float x = fmaf(lw, L, nb);
                x = fmaf(rw, R, x);
                x = fmaf(pw, L * R, x);
                x = fmaf(dw, L - R, x);
                v[i] = fast_tanh(x);
            }
        }
    }
    return v[0];
}

__global__ __launch_bounds__(256, 2) void k_roots(const u16* __restrict__ selwA,
                                                  const u16* __restrict__ basisTB,
                                                  const float* __restrict__ np_,
                                                  u16* __restrict__ roots) {
    __shared__ uint32_t st[4][32 * 12];   // per-wave repack, stride 12 dwords
    int tid = threadIdx.x, wid = tid >> 6, lane = tid & 63;
    int c = lane & 31, h = lane >> 5;
    int tile0 = blockIdx.x * 16 + wid * 4;   // 4 tiles per wave
    int w0w   = tile0 * 4;                   // wave's first tree (16 trees total)
    int t0b   = blockIdx.y * 512;
    float lw = np_[0], rw = np_[1], pw = np_[2], dw = np_[3], nb = np_[4];

    bhalf8 af[4];
    #pragma unroll
    for (int tl = 0; tl < 4; ++tl)
        af[tl] = *(const bhalf8*)(selwA + (size_t)((tile0 + tl) * 32 + c) * 16 + h * 8);

    uint32_t* myst = st[wid];
    for (int it = 0; it < 16; ++it) {
        int t0 = t0b + it * 32;
        bhalf8 bf = *(const bhalf8*)(basisTB + (size_t)(t0 + c) * 16 + h * 8);
        #pragma unroll
        for (int tl = 0; tl < 4; ++tl) {
            floatx16 z = {0.f,0.f,0.f,0.f,0.f,0.f,0.f,0.f,
                          0.f,0.f,0.f,0.f,0.f,0.f,0.f,0.f};
            floatx16 cc = __builtin_amdgcn_mfma_f32_32x32x16_bf16(af[tl], bf, z, 0, 0, 0);
            float vA[8], vB[8];
            #pragma unroll
            for (int l = 0; l < 8; ++l) { vA[l] = cc[l]; vB[l] = cc[8 + l]; }
            float rA = tree_eval(vA, lw, rw, pw, dw, nb);
            float rB = tree_eval(vB, lw, rw, pw, dw, nb);
            // dword j = tl*2+h holds trees w0w+2j (lo) and w0w+2j+1 (hi), token c
            myst[c * 12 + tl * 2 + h] = (uint32_t)f2bf(rA) | ((uint32_t)f2bf(rB) << 16);
        }
        __syncthreads();
        // lane: token = c, half h -> 16B of 8 trees
        uint4 q = *(const uint4*)(myst + c * 12 + h * 4);
        *(uint4*)(roots + (size_t)(t0 + c) * WTR + w0w + h * 8) = q;
        __syncthreads();
    }
}

// ---- kernel 3: out = roots @ out_w + out_b -----------------------------------
// BM=64 BN=128 BK=64 dbuf, grid (64,8)=512 blocks = 2/CU, one barrier/iter.
// XOR-swizzled 16B chunks kill the 128B-stride bank conflicts:
//   stage: chunk (row, s) <- global k-chunk s^(row&7)   (same 128B line per 8 lanes)
//   read : fragment k-chunk kc at LDS chunk row*8 + (kc^(row&7))
__global__ __launch_bounds__(256) void k_gemm(const u16* __restrict__ A,
                                              const u16* __restrict__ Bt,
                                              const float* __restrict__ out_b,
                                              float* __restrict__ C) {
    __shared__ __align__(16) u16 smA[2][64 * 64];    // 2 x 8 KB
    __shared__ __align__(16) u16 smB[2][128 * 64];   // 2 x 16 KB
    int tid = threadIdx.x;
    int bm = blockIdx.x * 64, bn = blockIdx.y * 128;
    int lane = tid & 63, wid = tid >> 6;
    int wm = (wid >> 1) * 32, wn = (wid & 1) * 64;

    floatx4 acc[2][4];
    #pragma unroll
    for (int i = 0; i < 2; ++i)
        #pragma unroll
        for (int j = 0; j < 4; ++j) acc[i][j] = (floatx4){0.f, 0.f, 0.f, 0.f};

    int ar = tid >> 3;                         // staging row 0..31
    int ak = ((tid & 7) ^ (ar & 7)) * 8;       // swizzled source k-chunk
    const u16* gA = A  + (size_t)(bm + ar) * KDIM + ak;
    const u16* gB = Bt + (size_t)(bn + ar) * KDIM + ak;

    int col = lane & 15, quad = lane >> 4, csw = col & 7;

    {   // preload iter 0 into buf 0
        char* ldA = (char*)smA[0] + tid * 16;
        char* ldB = (char*)smB[0] + tid * 16;
        load16(gA,                       ldA);
        load16(gA + (size_t)32 * KDIM,   ldA + 4096);
        load16(gB,                       ldB);
        load16(gB + (size_t)32 * KDIM,   ldB + 4096);
        load16(gB + (size_t)64 * KDIM,   ldB + 8192);
        load16(gB + (size_t)96 * KDIM,   ldB + 12288);
        gA += 64; gB += 64;
    }

    int cur = 0;
    for (int k0 = 0; k0 < KDIM / 64; ++k0) {
        __syncthreads();   // buf[cur] staged; buf[cur^1] free to overwrite
        if (k0 < KDIM / 64 - 1) {
            char* ldA = (char*)smA[cur ^ 1] + tid * 16;
            char* ldB = (char*)smB[cur ^ 1] + tid * 16;
            load16(gA,                       ldA);
            load16(gA + (size_t)32 * KDIM,   ldA + 4096);
            load16(gB,                       ldB);
            load16(gB + (size_t)32 * KDIM,   ldB + 4096);
            load16(gB + (size_t)64 * KDIM,   ldB + 8192);
            load16(gB + (size_t)96 * KDIM,   ldB + 12288);
            gA += 64; gB += 64;
        }
        const u16* sa = smA[cur];
        const u16* sb = smB[cur];
        #pragma unroll
        for (int kk = 0; kk < 2; ++kk) {
            int kc = kk * 4 + quad;
            bhalf8 af[2], bf[4];
            #pragma unroll
            for (int i = 0; i < 2; ++i)
                af[i] = *(const bhalf8*)(sa + ((wm + i * 16 + col) * 8 + (kc ^ csw)) * 8);
            #pragma unroll
            for (int j = 0; j < 4; ++j)
                bf[j] = *(const bhalf8*)(sb + ((wn + j * 16 + col) * 8 + (kc ^ csw)) * 8);
            #pragma unroll
            for (int i = 0; i < 2; ++i)
                #pragma unroll
                for (int j = 0; j < 4; ++j)
                    acc[i][j] = __builtin_amdgcn_mfma_f32_16x16x32_bf16(
                        af[i], bf[j], acc[i][j], 0, 0, 0);
        }
        cur ^= 1;
    }

    #pragma unroll
    for (int j = 0; j < 4; ++j) {
        int n = bn + wn + j * 16 + col;
        float bv = out_b[n];
        #pragma unroll
        for (int i = 0; i < 2; ++i) {
            int m0 = bm + wm + i * 16 + quad * 4;
            #pragma unroll
            for (int r = 0; r < 4; ++r)
                C[(size_t)(m0 + r) * DIM + n] = acc[i][j][r] + bv;
        }
    }
}

// ---------------- launcher ----------------------------------------------------
extern "C" void kernel_launch(void* const* d_in, const int* in_sizes, int n_in,
                              void* d_out, int out_size, void* d_ws, size_t ws_size,
                              hipStream_t stream) {
    const float* hidden      = (const float*)d_in[0];
    const float* slot_w      = (const float*)d_in[1];
    const float* slot_b      = (const float*)d_in[2];
    const float* leaf_logits = (const float*)d_in[3];
    const float* node_params = (const float*)d_in[4];
    const float* out_w       = (const float*)d_in[5];
    const float* out_b       = (const float*)d_in[6];
    float* out = (float*)d_out;

    char* ws = (char*)d_ws;
    u16* selwA   = (u16*)ws;                          // 32768*32B   = 1048576
    u16* basisTB = (u16*)(ws + 1048576);              // 4096*32B    = 131072
    u16* swT     = (u16*)(ws + 1179648);              // 16*1024*2   = 32768
    u16* outwt   = (u16*)(ws + 1212416);              // 1024*4096*2 = 8388608
    u16* roots   = (u16*)(ws + 9601024);              // 4096*4096*2 = 33554432

    k_prep <<<128 + 4096 + 8, 256, 0, stream>>>(leaf_logits, selwA, out_w, outwt, slot_w, swT);
    k_basis<<<BSZ / 16, 256, 0, stream>>>(hidden, swT, slot_b, basisTB);
    k_roots<<<dim3(64, 8), 256, 0, stream>>>(selwA, basisTB, node_params, roots);
    k_gemm <<<dim3(BSZ / 64, DIM / 128), 256, 0, stream>>>(roots, outwt, out_b, out);
}

// Round 7
// 205.106 us; speedup vs baseline: 1.2308x; 1.0082x over previous
//
#include <hip/hip_runtime.h>
#include <stdint.h>

// Problem constants (B=2,S=2048 -> BS=4096). ALL inputs/outputs are FP32.
#define BSZ   4096    // B*S tokens
#define DIM   1024    // D
#define WTR   4096    // W trees
#define KDIM  4096    // GEMM K == W
#define W8    32768   // W*8 leaf-rows

typedef unsigned short u16;
typedef __attribute__((ext_vector_type(8))) short bhalf8;     // 8 x bf16 (4 VGPRs)
typedef __attribute__((ext_vector_type(4))) float floatx4;    // 16x16 MFMA acc
typedef __attribute__((ext_vector_type(16))) float floatx16;  // 32x32 MFMA acc

__device__ __forceinline__ u16 f2bf(float f) {
    union { float f; uint32_t i; } v; v.f = f;
    uint32_t r = v.i + 0x7fffu + ((v.i >> 16) & 1u);   // round-nearest-even
    return (u16)(r >> 16);
}
// tanh(x) = 1 - 2/(exp2(x*2*log2e)+1)
__device__ __forceinline__ float fast_tanh(float x) {
    float e = __builtin_amdgcn_exp2f(x * 2.885390081777927f);
    return fmaf(-2.0f, __builtin_amdgcn_rcpf(e + 1.0f), 1.0f);
}
__device__ __forceinline__ void load16(const void* g, void* lds) {
    __builtin_amdgcn_global_load_lds(
        (const __attribute__((address_space(1))) uint32_t*)g,
        (__attribute__((address_space(3))) uint32_t*)lds, 16, 0, 0);
}

// ---- kernel 0 (fused prep): selector softmax -> bf16 A (PERMUTED rows);
//      out_w^T bf16; slot_w^T bf16; C init = out_b broadcast --------------------
// Leaf-row (w,l) at MFMA row p=(l&3)+8*(l>>2)+16*(q&1)+4*(q>>1), q=w&3, tile w>>2.
// After mfma_32x32x16, lane half h holds tree 2h in regs 0-7, tree 2h+1 in 8-15.
__global__ __launch_bounds__(256) void k_prep(const float* __restrict__ ll,
                                              u16* __restrict__ selwA,
                                              const float* __restrict__ ow,
                                              u16* __restrict__ owt,
                                              const float* __restrict__ slot_w,
                                              u16* __restrict__ swT,
                                              const float* __restrict__ out_b,
                                              float* __restrict__ C) {
    int bid = blockIdx.x, tid = threadIdx.x;
    if (bid < 128) {                       // ---- selector: 32768 rows
        int row = bid * 256 + tid;         // w*8 + l
        int w = row >> 3, l = row & 7, q = w & 3;
        int prow = (w >> 2) * 32 + (l & 3) + 8 * (l >> 2) + 16 * (q & 1) + 4 * (q >> 1);
        const float* p = ll + (size_t)row * 11;
        float v[11]; float m = -1e30f;
        #pragma unroll
        for (int c = 0; c < 11; ++c) { v[c] = p[c]; m = fmaxf(m, v[c]); }
        float s = 0.f;
        #pragma unroll
        for (int c = 0; c < 11; ++c) {
            v[c] = __builtin_amdgcn_exp2f((v[c] - m) * 1.4426950408889634f);
            s += v[c];
        }
        float inv = __builtin_amdgcn_rcpf(s);
        union { u16 h[16]; uint4 qq[2]; } o;
        #pragma unroll
        for (int c = 0; c < 8; ++c) o.h[c] = f2bf(v[c] * inv);
        o.h[8] = f2bf((v[10] - v[8]) * inv);   // consts -1,0,1 folded (basis k8=1)
        #pragma unroll
        for (int c = 9; c < 16; ++c) o.h[c] = 0;
        uint4* dst = (uint4*)(selwA + (size_t)prow * 16);
        dst[0] = o.qq[0]; dst[1] = o.qq[1];
    } else if (bid < 128 + 4096) {         // ---- out_w (W,D) -> owt (D,W) bf16
        int b = bid - 128;
        int d0 = (b & 31) * 32, w0 = (b >> 5) * 32;
        int tx = tid & 31, ty = tid >> 5;
        __shared__ float tile[32][33];
        #pragma unroll
        for (int i = 0; i < 32; i += 8)
            tile[ty + i][tx] = ow[(size_t)(w0 + ty + i) * DIM + d0 + tx];
        __syncthreads();
        #pragma unroll
        for (int i = 0; i < 32; i += 8)
            owt[(size_t)(d0 + ty + i) * WTR + w0 + tx] = f2bf(tile[tx][ty + i]);
    } else if (bid < 128 + 4096 + 8) {     // ---- slot_w (D,8) -> swT (16,D) bf16
        int b = bid - 128 - 4096;
        for (int it = 0; it < 8; ++it) {
            int idx = b * 2048 + it * 256 + tid;
            int s = idx >> 10, d = idx & 1023;
            float val = (s < 8) ? slot_w[(size_t)d * 8 + s] : 0.f;
            swT[(size_t)s * DIM + d] = f2bf(val);
        }
    } else {                               // ---- C init: C[r][n] = out_b[n]
        int b = bid - 128 - 4096 - 8;      // 256 blocks x 16 rows
        float4 bv = *(const float4*)(out_b + (tid & 255) * 4);
        #pragma unroll
        for (int it = 0; it < 16; ++it) {
            size_t flat = (size_t)b * 16384 + it * 1024 + (tid & 255) * 4;
            *(float4*)(C + flat) = bv;
        }
    }
}

// ---- kernel 1: basisTB[t][16] bf16 via MFMA, 4 waves K-split + LDS reduce ----
__global__ __launch_bounds__(256) void k_basis(const float* __restrict__ hidden,
                                               const u16* __restrict__ swT,
                                               const float* __restrict__ slot_b,
                                               u16* __restrict__ basisTB) {
    int m0 = blockIdx.x * 16;
    int tid = threadIdx.x, lane = tid & 63, wid = tid >> 6;
    int col = lane & 15, quad = lane >> 4;
    const float* ga = hidden + (size_t)(m0 + col) * DIM + wid * 256 + quad * 8;
    const u16*   gb = swT + (size_t)col * DIM + wid * 256 + quad * 8;
    floatx4 acc = (floatx4){0.f, 0.f, 0.f, 0.f};
    #pragma unroll
    for (int k0 = 0; k0 < 256; k0 += 32) {
        float4 a0 = *(const float4*)(ga + k0);
        float4 a1 = *(const float4*)(ga + k0 + 4);
        bhalf8 bf = *(const bhalf8*)(gb + k0);
        bhalf8 af;
        af[0] = (short)f2bf(a0.x); af[1] = (short)f2bf(a0.y);
        af[2] = (short)f2bf(a0.z); af[3] = (short)f2bf(a0.w);
        af[4] = (short)f2bf(a1.x); af[5] = (short)f2bf(a1.y);
        af[6] = (short)f2bf(a1.z); af[7] = (short)f2bf(a1.w);
        acc = __builtin_amdgcn_mfma_f32_16x16x32_bf16(af, bf, acc, 0, 0, 0);
    }
    __shared__ float smr[4][16][16];   // [wave][token][col]
    #pragma unroll
    for (int r = 0; r < 4; ++r) smr[wid][quad * 4 + r][col] = acc[r];
    __syncthreads();
    int tt = tid >> 4, cc = tid & 15;
    float s = smr[0][tt][cc] + smr[1][tt][cc] + smr[2][tt][cc] + smr[3][tt][cc];
    u16 val;
    if (cc < 8)       val = f2bf(fast_tanh(s + slot_b[cc]));
    else if (cc == 8) val = (u16)0x3f80;   // bf16 1.0
    else              val = 0;
    basisTB[(size_t)(m0 + tt) * 16 + cc] = val;
}

// ---- kernel 2: roots via MFMA einsum (permuted A) + in-register tree ---------
// Block = 64 trees (16 tiles) x 512 tokens. Block-wide padded LDS repack ->
// 128 B contiguous stores per token row; dbuf LDS -> ONE barrier per strip.
__device__ __forceinline__ float tree_eval(float v[8], float lw, float rw,
                                           float pw, float dw, float nb) {
    #pragma unroll
    for (int lev = 0; lev < 3; ++lev) {
        int n = 4 >> lev;
        #pragma unroll
        for (int i = 0; i < 4; ++i) {
            if (i < n) {
                float L = v[2*i], R = v[2*i+1];
                float x = fmaf(lw, L, nb);
                x = fmaf(rw, R, x);
                x = fmaf(pw, L * R, x);
                x = fmaf(dw, L - R, x);
                v[i] = fast_tanh(x);
            }
        }
    }
    return v[0];
}

__global__ __launch_bounds__(256, 2) void k_roots(const u16* __restrict__ selwA,
                                                  const u16* __restrict__ basisTB,
                                                  const float* __restrict__ np_,
                                                  u16* __restrict__ roots) {
    __shared__ uint32_t st[2][32 * 33];   // [buf][token*33 + pair], stride 33
    int tid = threadIdx.x, wid = tid >> 6, lane = tid & 63;
    int c = lane & 31, h = lane >> 5;
    int tile0 = blockIdx.x * 16 + wid * 4;   // 4 tiles per wave, 16 per block
    int wblk  = blockIdx.x * 64;             // block's first tree
    int t0b   = blockIdx.y * 512;
    float lw = np_[0], rw = np_[1], pw = np_[2], dw = np_[3], nb = np_[4];

    bhalf8 af[4];
    #pragma unroll
    for (int tl = 0; tl < 4; ++tl)
        af[tl] = *(const bhalf8*)(selwA + (size_t)((tile0 + tl) * 32 + c) * 16 + h * 8);

    int tok = tid >> 3, ch = tid & 7;        // store-phase role
    for (int it = 0; it < 16; ++it) {
        int t0 = t0b + it * 32;
        uint32_t* buf = st[it & 1];
        bhalf8 bf = *(const bhalf8*)(basisTB + (size_t)(t0 + c) * 16 + h * 8);
        #pragma unroll
        for (int tl = 0; tl < 4; ++tl) {
            floatx16 z = {0.f,0.f,0.f,0.f,0.f,0.f,0.f,0.f,
                          0.f,0.f,0.f,0.f,0.f,0.f,0.f,0.f};
            floatx16 cc = __builtin_amdgcn_mfma_f32_32x32x16_bf16(af[tl], bf, z, 0, 0, 0);
            float vA[8], vB[8];
            #pragma unroll
            for (int l = 0; l < 8; ++l) { vA[l] = cc[l]; vB[l] = cc[8 + l]; }
            float rA = tree_eval(vA, lw, rw, pw, dw, nb);
            float rB = tree_eval(vB, lw, rw, pw, dw, nb);
            // pair index = wid*8 + tl*2 + h -> trees wblk + 2*pair, +1; token c
            buf[c * 33 + wid * 8 + tl * 2 + h] =
                (uint32_t)f2bf(rA) | ((uint32_t)f2bf(rB) << 16);
        }
        __syncthreads();
        // store: 8 threads per token cover 128 B contiguous
        uint32_t d0 = buf[tok * 33 + ch * 4];
        uint32_t d1 = buf[tok * 33 + ch * 4 + 1];
        uint32_t d2 = buf[tok * 33 + ch * 4 + 2];
        uint32_t d3 = buf[tok * 33 + ch * 4 + 3];
        uint4 q; q.x = d0; q.y = d1; q.z = d2; q.w = d3;
        *(uint4*)(roots + (size_t)(t0 + tok) * WTR + wblk + ch * 8) = q;
        // no 2nd barrier: next strip writes the other buffer
    }
}

// ---- kernel 3: C += split-K partial of roots @ out_w  (atomic f32) -----------
// BM=64 BN=128 BK=64 single-buf (24 KB LDS), grid (64,8,2)=1024 blocks=4/CU.
// XOR-swizzled 16B chunks (verified 0 conflicts in round 6).
__global__ __launch_bounds__(256) void k_gemm(const u16* __restrict__ A,
                                              const u16* __restrict__ Bt,
                                              float* __restrict__ C) {
    __shared__ __align__(16) u16 smA[64 * 64];    // 8 KB
    __shared__ __align__(16) u16 smB[128 * 64];   // 16 KB
    int tid = threadIdx.x;
    int bm = blockIdx.x * 64, bn = blockIdx.y * 128;
    int koff = blockIdx.z * (KDIM / 2);
    int lane = tid & 63, wid = tid >> 6;
    int wm = (wid >> 1) * 32, wn = (wid & 1) * 64;

    floatx4 acc[2][4];
    #pragma unroll
    for (int i = 0; i < 2; ++i)
        #pragma unroll
        for (int j = 0; j < 4; ++j) acc[i][j] = (floatx4){0.f, 0.f, 0.f, 0.f};

    int ar = tid >> 3;                         // staging row 0..31
    int ak = ((tid & 7) ^ (ar & 7)) * 8;       // swizzled source k-chunk
    const u16* gA = A  + (size_t)(bm + ar) * KDIM + koff + ak;
    const u16* gB = Bt + (size_t)(bn + ar) * KDIM + koff + ak;
    char* ldA = (char*)smA + tid * 16;
    char* ldB = (char*)smB + tid * 16;

    int col = lane & 15, quad = lane >> 4, csw = col & 7;

    for (int k0 = 0; k0 < KDIM / 2 / 64; ++k0) {
        __syncthreads();                       // prev iter's ds_reads done
        load16(gA,                       ldA);
        load16(gA + (size_t)32 * KDIM,   ldA + 4096);
        load16(gB,                       ldB);
        load16(gB + (size_t)32 * KDIM,   ldB + 4096);
        load16(gB + (size_t)64 * KDIM,   ldB + 8192);
        load16(gB + (size_t)96 * KDIM,   ldB + 12288);
        gA += 64; gB += 64;
        __syncthreads();                       // drain vmcnt (hidden by 4 blk/CU)

        #pragma unroll
        for (int kk = 0; kk < 2; ++kk) {
            int kc = kk * 4 + quad;
            bhalf8 af[2], bf[4];
            #pragma unroll
            for (int i = 0; i < 2; ++i)
                af[i] = *(const bhalf8*)(smA + ((wm + i * 16 + col) * 8 + (kc ^ csw)) * 8);
            #pragma unroll
            for (int j = 0; j < 4; ++j)
                bf[j] = *(const bhalf8*)(smB + ((wn + j * 16 + col) * 8 + (kc ^ csw)) * 8);
            #pragma unroll
            for (int i = 0; i < 2; ++i)
                #pragma unroll
                for (int j = 0; j < 4; ++j)
                    acc[i][j] = __builtin_amdgcn_mfma_f32_16x16x32_bf16(
                        af[i], bf[j], acc[i][j], 0, 0, 0);
        }
    }

    #pragma unroll
    for (int j = 0; j < 4; ++j) {
        int n = bn + wn + j * 16 + col;
        #pragma unroll
        for (int i = 0; i < 2; ++i) {
            int m0 = bm + wm + i * 16 + quad * 4;
            #pragma unroll
            for (int r = 0; r < 4; ++r)
                atomicAdd(&C[(size_t)(m0 + r) * DIM + n], acc[i][j][r]);
        }
    }
}

// ---------------- launcher ----------------------------------------------------
extern "C" void kernel_launch(void* const* d_in, const int* in_sizes, int n_in,
                              void* d_out, int out_size, void* d_ws, size_t ws_size,
                              hipStream_t stream) {
    const float* hidden      = (const float*)d_in[0];
    const float* slot_w      = (const float*)d_in[1];
    const float* slot_b      = (const float*)d_in[2];
    const float* leaf_logits = (const float*)d_in[3];
    const float* node_params = (const float*)d_in[4];
    const float* out_w       = (const float*)d_in[5];
    const float* out_b       = (const float*)d_in[6];
    float* out = (float*)d_out;

    char* ws = (char*)d_ws;
    u16* selwA   = (u16*)ws;                          // 32768*32B   = 1048576
    u16* basisTB = (u16*)(ws + 1048576);              // 4096*32B    = 131072
    u16* swT     = (u16*)(ws + 1179648);              // 16*1024*2   = 32768
    u16* outwt   = (u16*)(ws + 1212416);              // 1024*4096*2 = 8388608
    u16* roots   = (u16*)(ws + 9601024);              // 4096*4096*2 = 33554432

    k_prep <<<128 + 4096 + 8 + 256, 256, 0, stream>>>(leaf_logits, selwA, out_w, outwt,
                                                      slot_w, swT, out_b, out);
    k_basis<<<BSZ / 16, 256, 0, stream>>>(hidden, swT, slot_b, basisTB);
    k_roots<<<dim3(64, 8), 256, 0, stream>>>(selwA, basisTB, node_params, roots);
    k_gemm <<<dim3(BSZ / 64, DIM / 128, 2), 256, 0, stream>>>(roots, outwt, out);
}

// Round 8
// 190.770 us; speedup vs baseline: 1.3233x; 1.0751x over previous
//
#include <hip/hip_runtime.h>
#include <stdint.h>

// Problem constants (B=2,S=2048 -> BS=4096). ALL inputs/outputs are FP32.
#define BSZ   4096    // B*S tokens
#define DIM   1024    // D
#define WTR   4096    // W trees
#define KDIM  4096    // GEMM K == W
#define W8    32768   // W*8 leaf-rows

typedef unsigned short u16;
typedef __attribute__((ext_vector_type(8))) short bhalf8;     // 8 x bf16 (4 VGPRs)
typedef __attribute__((ext_vector_type(4))) float floatx4;    // 16x16 MFMA acc
typedef __attribute__((ext_vector_type(16))) float floatx16;  // 32x32 MFMA acc

__device__ __forceinline__ u16 f2bf(float f) {
    union { float f; uint32_t i; } v; v.f = f;
    uint32_t r = v.i + 0x7fffu + ((v.i >> 16) & 1u);   // round-nearest-even
    return (u16)(r >> 16);
}
// tanh(x) = 1 - 2/(exp2(x*2*log2e)+1)
__device__ __forceinline__ float fast_tanh(float x) {
    float e = __builtin_amdgcn_exp2f(x * 2.885390081777927f);
    return fmaf(-2.0f, __builtin_amdgcn_rcpf(e + 1.0f), 1.0f);
}
__device__ __forceinline__ void load16(const void* g, void* lds) {
    __builtin_amdgcn_global_load_lds(
        (const __attribute__((address_space(1))) uint32_t*)g,
        (__attribute__((address_space(3))) uint32_t*)lds, 16, 0, 0);
}

// ---- kernel 0 (fused prep): selector softmax -> bf16 A (PERMUTED rows);
//      out_w^T bf16; slot_w^T bf16; C init = out_b broadcast --------------------
__global__ __launch_bounds__(256) void k_prep(const float* __restrict__ ll,
                                              u16* __restrict__ selwA,
                                              const float* __restrict__ ow,
                                              u16* __restrict__ owt,
                                              const float* __restrict__ slot_w,
                                              u16* __restrict__ swT,
                                              const float* __restrict__ out_b,
                                              float* __restrict__ C) {
    int bid = blockIdx.x, tid = threadIdx.x;
    if (bid < 128) {                       // ---- selector: 32768 rows
        int row = bid * 256 + tid;         // w*8 + l
        int w = row >> 3, l = row & 7, q = w & 3;
        int prow = (w >> 2) * 32 + (l & 3) + 8 * (l >> 2) + 16 * (q & 1) + 4 * (q >> 1);
        const float* p = ll + (size_t)row * 11;
        float v[11]; float m = -1e30f;
        #pragma unroll
        for (int c = 0; c < 11; ++c) { v[c] = p[c]; m = fmaxf(m, v[c]); }
        float s = 0.f;
        #pragma unroll
        for (int c = 0; c < 11; ++c) {
            v[c] = __builtin_amdgcn_exp2f((v[c] - m) * 1.4426950408889634f);
            s += v[c];
        }
        float inv = __builtin_amdgcn_rcpf(s);
        union { u16 h[16]; uint4 qq[2]; } o;
        #pragma unroll
        for (int c = 0; c < 8; ++c) o.h[c] = f2bf(v[c] * inv);
        o.h[8] = f2bf((v[10] - v[8]) * inv);   // consts -1,0,1 folded (basis k8=1)
        #pragma unroll
        for (int c = 9; c < 16; ++c) o.h[c] = 0;
        uint4* dst = (uint4*)(selwA + (size_t)prow * 16);
        dst[0] = o.qq[0]; dst[1] = o.qq[1];
    } else if (bid < 128 + 4096) {         // ---- out_w (W,D) -> owt (D,W) bf16
        int b = bid - 128;
        int d0 = (b & 31) * 32, w0 = (b >> 5) * 32;
        int tx = tid & 31, ty = tid >> 5;
        __shared__ float tile[32][33];
        #pragma unroll
        for (int i = 0; i < 32; i += 8)
            tile[ty + i][tx] = ow[(size_t)(w0 + ty + i) * DIM + d0 + tx];
        __syncthreads();
        #pragma unroll
        for (int i = 0; i < 32; i += 8)
            owt[(size_t)(d0 + ty + i) * WTR + w0 + tx] = f2bf(tile[tx][ty + i]);
    } else if (bid < 128 + 4096 + 8) {     // ---- slot_w (D,8) -> swT (16,D) bf16
        int b = bid - 128 - 4096;
        for (int it = 0; it < 8; ++it) {
            int idx = b * 2048 + it * 256 + tid;
            int s = idx >> 10, d = idx & 1023;
            float val = (s < 8) ? slot_w[(size_t)d * 8 + s] : 0.f;
            swT[(size_t)s * DIM + d] = f2bf(val);
        }
    } else {                               // ---- C init: C[r][n] = out_b[n]
        int b = bid - 128 - 4096 - 8;      // 256 blocks x 16 rows
        float4 bv = *(const float4*)(out_b + (tid & 255) * 4);
        #pragma unroll
        for (int it = 0; it < 16; ++it) {
            size_t flat = (size_t)b * 16384 + it * 1024 + (tid & 255) * 4;
            *(float4*)(C + flat) = bv;
        }
    }
}

// ---- kernel 1: basisTB[t][16] bf16 via MFMA, 4 waves K-split + LDS reduce ----
__global__ __launch_bounds__(256) void k_basis(const float* __restrict__ hidden,
                                               const u16* __restrict__ swT,
                                               const float* __restrict__ slot_b,
                                               u16* __restrict__ basisTB) {
    int m0 = blockIdx.x * 16;
    int tid = threadIdx.x, lane = tid & 63, wid = tid >> 6;
    int col = lane & 15, quad = lane >> 4;
    const float* ga = hidden + (size_t)(m0 + col) * DIM + wid * 256 + quad * 8;
    const u16*   gb = swT + (size_t)col * DIM + wid * 256 + quad * 8;
    floatx4 acc = (floatx4){0.f, 0.f, 0.f, 0.f};
    #pragma unroll
    for (int k0 = 0; k0 < 256; k0 += 32) {
        float4 a0 = *(const float4*)(ga + k0);
        float4 a1 = *(const float4*)(ga + k0 + 4);
        bhalf8 bf = *(const bhalf8*)(gb + k0);
        bhalf8 af;
        af[0] = (short)f2bf(a0.x); af[1] = (short)f2bf(a0.y);
        af[2] = (short)f2bf(a0.z); af[3] = (short)f2bf(a0.w);
        af[4] = (short)f2bf(a1.x); af[5] = (short)f2bf(a1.y);
        af[6] = (short)f2bf(a1.z); af[7] = (short)f2bf(a1.w);
        acc = __builtin_amdgcn_mfma_f32_16x16x32_bf16(af, bf, acc, 0, 0, 0);
    }
    __shared__ float smr[4][16][16];   // [wave][token][col]
    #pragma unroll
    for (int r = 0; r < 4; ++r) smr[wid][quad * 4 + r][col] = acc[r];
    __syncthreads();
    int tt = tid >> 4, cc = tid & 15;
    float s = smr[0][tt][cc] + smr[1][tt][cc] + smr[2][tt][cc] + smr[3][tt][cc];
    u16 val;
    if (cc < 8)       val = f2bf(fast_tanh(s + slot_b[cc]));
    else if (cc == 8) val = (u16)0x3f80;   // bf16 1.0
    else              val = 0;
    basisTB[(size_t)(m0 + tt) * 16 + cc] = val;
}

// ---- kernel 2: roots via MFMA einsum (permuted A) + in-register tree ---------
// Node refactor: x = L*(lw+dw+pw*R) + (rw-dw)*R + nb, tanh scale folded:
//   y = 2log2e*x = L*fmaf(A2,R,A1) + fmaf(A3,R,A4); tanh = 1 - 2*rcp(exp2(y)+1)
__device__ __forceinline__ float tree_eval(float v[8], float A1, float A2,
                                           float A3, float A4) {
    #pragma unroll
    for (int lev = 0; lev < 3; ++lev) {
        int n = 4 >> lev;
        #pragma unroll
        for (int i = 0; i < 4; ++i) {
            if (i < n) {
                float L = v[2*i], R = v[2*i+1];
                float u = fmaf(A2, R, A1);
                float w = fmaf(A3, R, A4);
                float y = fmaf(L, u, w);
                float e = __builtin_amdgcn_exp2f(y);
                v[i] = fmaf(-2.0f, __builtin_amdgcn_rcpf(e + 1.0f), 1.0f);
            }
        }
    }
    return v[0];
}

__global__ __launch_bounds__(256, 2) void k_roots(const u16* __restrict__ selwA,
                                                  const u16* __restrict__ basisTB,
                                                  const float* __restrict__ np_,
                                                  u16* __restrict__ roots) {
    __shared__ uint32_t st[2][32 * 33];   // [buf][token*33 + pair], stride 33
    int tid = threadIdx.x, wid = tid >> 6, lane = tid & 63;
    int c = lane & 31, h = lane >> 5;
    int tile0 = blockIdx.x * 16 + wid * 4;   // 4 tiles per wave, 16 per block
    int wblk  = blockIdx.x * 64;             // block's first tree
    int t0b   = blockIdx.y * 512;
    float lw = np_[0], rw = np_[1], pw = np_[2], dw = np_[3], nb = np_[4];
    const float c2 = 2.885390081777927f;     // 2*log2(e)
    float A1 = (lw + dw) * c2, A2 = pw * c2, A3 = (rw - dw) * c2, A4 = nb * c2;

    bhalf8 af[4];
    #pragma unroll
    for (int tl = 0; tl < 4; ++tl)
        af[tl] = *(const bhalf8*)(selwA + (size_t)((tile0 + tl) * 32 + c) * 16 + h * 8);

    int tok = tid >> 3, ch = tid & 7;        // store-phase role
    for (int it = 0; it < 16; ++it) {
        int t0 = t0b + it * 32;
        uint32_t* buf = st[it & 1];
        bhalf8 bf = *(const bhalf8*)(basisTB + (size_t)(t0 + c) * 16 + h * 8);
        #pragma unroll
        for (int tl = 0; tl < 4; ++tl) {
            floatx16 z = {0.f,0.f,0.f,0.f,0.f,0.f,0.f,0.f,
                          0.f,0.f,0.f,0.f,0.f,0.f,0.f,0.f};
            floatx16 cc = __builtin_amdgcn_mfma_f32_32x32x16_bf16(af[tl], bf, z, 0, 0, 0);
            float vA[8], vB[8];
            #pragma unroll
            for (int l = 0; l < 8; ++l) { vA[l] = cc[l]; vB[l] = cc[8 + l]; }
            float rA = tree_eval(vA, A1, A2, A3, A4);
            float rB = tree_eval(vB, A1, A2, A3, A4);
            buf[c * 33 + wid * 8 + tl * 2 + h] =
                (uint32_t)f2bf(rA) | ((uint32_t)f2bf(rB) << 16);
        }
        __syncthreads();
        uint32_t d0 = buf[tok * 33 + ch * 4];
        uint32_t d1 = buf[tok * 33 + ch * 4 + 1];
        uint32_t d2 = buf[tok * 33 + ch * 4 + 2];
        uint32_t d3 = buf[tok * 33 + ch * 4 + 3];
        uint4 q; q.x = d0; q.y = d1; q.z = d2; q.w = d3;
        *(uint4*)(roots + (size_t)(t0 + tok) * WTR + wblk + ch * 8) = q;
    }
}

// ---- kernel 3: C += split-K partial of roots @ out_w  (atomic f32) -----------
// BM=128 BN=128 BK=64 single-buf (32 KB LDS), grid (32,8,2)=512 blocks=2/CU.
// Wave tile 64x64: 16 ds_read_b128 per 32 MFMA per K-iter (balanced pipes).
// XOR-swizzled 16B chunks (zero conflicts, verified rounds 6-7).
__global__ __launch_bounds__(256) void k_gemm(const u16* __restrict__ A,
                                              const u16* __restrict__ Bt,
                                              float* __restrict__ C) {
    __shared__ __align__(16) u16 smA[128 * 64];   // 16 KB
    __shared__ __align__(16) u16 smB[128 * 64];   // 16 KB
    int tid = threadIdx.x;
    int bm = blockIdx.x * 128, bn = blockIdx.y * 128;
    int koff = blockIdx.z * (KDIM / 2);
    int lane = tid & 63, wid = tid >> 6;
    int wm = (wid >> 1) * 64, wn = (wid & 1) * 64;

    floatx4 acc[4][4];
    #pragma unroll
    for (int i = 0; i < 4; ++i)
        #pragma unroll
        for (int j = 0; j < 4; ++j) acc[i][j] = (floatx4){0.f, 0.f, 0.f, 0.f};

    int ar = tid >> 3;                         // staging row 0..31 (+32 per rep)
    int ak = ((tid & 7) ^ (ar & 7)) * 8;       // swizzled source k-chunk
    const u16* gA = A  + (size_t)(bm + ar) * KDIM + koff + ak;
    const u16* gB = Bt + (size_t)(bn + ar) * KDIM + koff + ak;
    char* ldA = (char*)smA + tid * 16;
    char* ldB = (char*)smB + tid * 16;

    int col = lane & 15, quad = lane >> 4, csw = col & 7;

    for (int k0 = 0; k0 < KDIM / 2 / 64; ++k0) {
        __syncthreads();                       // prev iter's ds_reads done
        load16(gA,                       ldA);
        load16(gA + (size_t)32 * KDIM,   ldA + 4096);
        load16(gA + (size_t)64 * KDIM,   ldA + 8192);
        load16(gA + (size_t)96 * KDIM,   ldA + 12288);
        load16(gB,                       ldB);
        load16(gB + (size_t)32 * KDIM,   ldB + 4096);
        load16(gB + (size_t)64 * KDIM,   ldB + 8192);
        load16(gB + (size_t)96 * KDIM,   ldB + 12288);
        gA += 64; gB += 64;
        __syncthreads();                       // drain vmcnt (hidden by 2 blk/CU)

        #pragma unroll
        for (int kk = 0; kk < 2; ++kk) {
            int kc = kk * 4 + quad;
            bhalf8 af[4], bf[4];
            #pragma unroll
            for (int i = 0; i < 4; ++i)
                af[i] = *(const bhalf8*)(smA + ((wm + i * 16 + col) * 8 + (kc ^ csw)) * 8);
            #pragma unroll
            for (int j = 0; j < 4; ++j)
                bf[j] = *(const bhalf8*)(smB + ((wn + j * 16 + col) * 8 + (kc ^ csw)) * 8);
            #pragma unroll
            for (int i = 0; i < 4; ++i)
                #pragma unroll
                for (int j = 0; j < 4; ++j)
                    acc[i][j] = __builtin_amdgcn_mfma_f32_16x16x32_bf16(
                        af[i], bf[j], acc[i][j], 0, 0, 0);
        }
    }

    #pragma unroll
    for (int j = 0; j < 4; ++j) {
        int n = bn + wn + j * 16 + col;
        #pragma unroll
        for (int i = 0; i < 4; ++i) {
            int m0 = bm + wm + i * 16 + quad * 4;
            #pragma unroll
            for (int r = 0; r < 4; ++r)
                atomicAdd(&C[(size_t)(m0 + r) * DIM + n], acc[i][j][r]);
        }
    }
}

// ---------------- launcher ----------------------------------------------------
extern "C" void kernel_launch(void* const* d_in, const int* in_sizes, int n_in,
                              void* d_out, int out_size, void* d_ws, size_t ws_size,
                              hipStream_t stream) {
    const float* hidden      = (const float*)d_in[0];
    const float* slot_w      = (const float*)d_in[1];
    const float* slot_b      = (const float*)d_in[2];
    const float* leaf_logits = (const float*)d_in[3];
    const float* node_params = (const float*)d_in[4];
    const float* out_w       = (const float*)d_in[5];
    const float* out_b       = (const float*)d_in[6];
    float* out = (float*)d_out;

    char* ws = (char*)d_ws;
    u16* selwA   = (u16*)ws;                          // 32768*32B   = 1048576
    u16* basisTB = (u16*)(ws + 1048576);              // 4096*32B    = 131072
    u16* swT     = (u16*)(ws + 1179648);              // 16*1024*2   = 32768
    u16* outwt   = (u16*)(ws + 1212416);              // 1024*4096*2 = 8388608
    u16* roots   = (u16*)(ws + 9601024);              // 4096*4096*2 = 33554432

    k_prep <<<128 + 4096 + 8 + 256, 256, 0, stream>>>(leaf_logits, selwA, out_w, outwt,
                                                      slot_w, swT, out_b, out);
    k_basis<<<BSZ / 16, 256, 0, stream>>>(hidden, swT, slot_b, basisTB);
    k_roots<<<dim3(64, 8), 256, 0, stream>>>(selwA, basisTB, node_params, roots);
    k_gemm <<<dim3(BSZ / 128, DIM / 128, 2), 256, 0, stream>>>(roots, outwt, out);
}